// Round 3
// baseline (238.942 us; speedup 1.0000x reference)
//
#include <hip/hip_runtime.h>

// IF (integrate-and-fire) SNN forward scan.
// x: [T*B, C, H, W] fp32 viewed as [T=8, slice=4,194,304 floats]; out same shape.
// Per element n: mem=0.5*thr; for t: mem+=x[t][n]; sp=(mem>=thr)?thr:0; mem-=sp.
//
// R1: one float4/thread, one-shot grid      -> 90 us, eff 3.0 TB/s
// R2: ILP=2 + nt stores                     -> 83 us, eff 3.2 TB/s (burst theory wrong;
//     FETCH unchanged; harness memset hits 6.57 TB/s on same device)
// R3: persistent grid-stride loop (1024 blocks, 4 iters/thread): steady-state
//     read+write overlap across iterations, no one-shot ramp/drain. nt hints on
//     loads+stores.

typedef float f4 __attribute__((ext_vector_type(4)));

constexpr int T_STEPS = 8;
constexpr int BLOCK   = 256;
constexpr int GRID    = 1024;   // 4 blocks/CU resident (28-32 VGPR), 4 iters/thread

__global__ __launch_bounds__(BLOCK) void if_fwd_kernel(
    const f4* __restrict__ x,
    const float* __restrict__ thresh,
    f4* __restrict__ out,
    int stride4)   // float4s per timestep slice
{
    const int tid      = blockIdx.x * BLOCK + threadIdx.x;
    const int nthreads = GRID * BLOCK;
    const float thr    = thresh[0];      // wave-uniform -> scalar load
    const float h      = 0.5f * thr;

    for (int i = tid; i < stride4; i += nthreads) {
        // 8 independent 16B loads in flight; next iteration's loads overlap
        // this iteration's stores (no barrier, no aliasing).
        f4 xt[T_STEPS];
#pragma unroll
        for (int t = 0; t < T_STEPS; ++t) {
            xt[t] = __builtin_nontemporal_load(x + (size_t)t * stride4 + i);
        }

        f4 m = {h, h, h, h};
#pragma unroll
        for (int t = 0; t < T_STEPS; ++t) {
            m += xt[t];
            f4 s;
#pragma unroll
            for (int k = 0; k < 4; ++k) {
                s[k] = (m[k] >= thr) ? thr : 0.0f;
            }
            m -= s;
            __builtin_nontemporal_store(s, out + (size_t)t * stride4 + i);
        }
    }
}

extern "C" void kernel_launch(void* const* d_in, const int* in_sizes, int n_in,
                              void* d_out, int out_size, void* d_ws, size_t ws_size,
                              hipStream_t stream) {
    const float* x      = (const float*)d_in[0];   // [T*B, C, H, W] fp32
    const float* thresh = (const float*)d_in[1];   // scalar threshold (1 elem)
    float* out          = (float*)d_out;

    const int total   = in_sizes[0];       // 33,554,432
    const int stride  = total / T_STEPS;   // 4,194,304 elems per slice
    const int stride4 = stride / 4;        // 1,048,576 float4s per slice

    if_fwd_kernel<<<dim3(GRID), dim3(BLOCK), 0, stream>>>(
        (const f4*)x, thresh, (f4*)out, stride4);
}